// Round 1
// baseline (134.491 us; speedup 1.0000x reference)
//
#include <hip/hip_runtime.h>

// DilatedAvgPooling: 3x3 kernel, dilation=2, padding=2, stride=1, mean over
// 9 taps INCLUDING zero-padded taps. Input (16,256,128,128) fp32,
// output (16,256,128,128,1) fp32 (same flat layout).
//
// Separable rolling-window implementation:
//   hs[h][w] = x[h][w-2] + x[h][w] + x[h][w+2]   (zero outside)
//   out[h][w] = (hs[h-2][w] + hs[h][w] + hs[h+2][w]) / 9
// Each thread owns a 4-wide (float4) column strip over a 32-row chunk of one
// (b,c) plane, keeping a 4-deep register history of hs rows.

#define HDIM 128
#define WDIM 128
#define CHUNK 32          // rows per thread
#define NCHUNK (HDIM / CHUNK)
#define NQUAD (WDIM / 4)  // float4 quads per row

__global__ __launch_bounds__(256) void dilated_avg_kernel(
    const float* __restrict__ x, float* __restrict__ out, int total_threads) {
  int g = blockIdx.x * blockDim.x + threadIdx.x;
  if (g >= total_threads) return;

  const int wq    = g & (NQUAD - 1);          // w-quad index (fastest -> coalesced)
  const int chunk = (g >> 5) & (NCHUNK - 1);  // row chunk
  const int plane = g >> 7;                   // b*C + c

  const float* __restrict__ xp = x + (size_t)plane * (HDIM * WDIM);
  float* __restrict__ op       = out + (size_t)plane * (HDIM * WDIM);

  const int w0 = wq * 4;
  const int h0 = chunk * CHUNK;
  const bool has_l = (w0 >= 2);           // false only for w0 == 0
  const bool has_r = (w0 + 5 < WDIM);     // false only for w0 == 124

  const float ninth = 1.0f / 9.0f;

  float4 p1 = {0,0,0,0}, p2 = {0,0,0,0}, p3 = {0,0,0,0}, p4 = {0,0,0,0};

  // step t: r = h0 - 2 + t is the input row whose horizontal sum we compute.
  // after computing cur = hs[r], output row (r-2) = p4 + p2 + cur (needs t>=4).
  #pragma unroll 4
  for (int t = 0; t < CHUNK + 4; ++t) {
    const int r = h0 - 2 + t;
    float4 c4 = {0,0,0,0};
    float2 l2 = {0,0};
    float2 r2 = {0,0};
    if (r >= 0 && r < HDIM) {
      const float* row = xp + r * WDIM + w0;
      c4 = *reinterpret_cast<const float4*>(row);
      if (has_l) l2 = *reinterpret_cast<const float2*>(row - 2);
      if (has_r) r2 = *reinterpret_cast<const float2*>(row + 4);
    }
    float4 cur;
    cur.x = l2.x + c4.x + c4.z;
    cur.y = l2.y + c4.y + c4.w;
    cur.z = c4.x + c4.z + r2.x;
    cur.w = c4.y + c4.w + r2.y;

    if (t >= 4) {
      float4 o;
      o.x = (p4.x + p2.x + cur.x) * ninth;
      o.y = (p4.y + p2.y + cur.y) * ninth;
      o.z = (p4.z + p2.z + cur.z) * ninth;
      o.w = (p4.w + p2.w + cur.w) * ninth;
      *reinterpret_cast<float4*>(op + (r - 2) * WDIM + w0) = o;
    }
    p4 = p3; p3 = p2; p2 = p1; p1 = cur;
  }
}

extern "C" void kernel_launch(void* const* d_in, const int* in_sizes, int n_in,
                              void* d_out, int out_size, void* d_ws, size_t ws_size,
                              hipStream_t stream) {
  const float* x = (const float*)d_in[0];
  float* out = (float*)d_out;

  // planes = B*C = in_size / (H*W)
  const int planes = in_sizes[0] / (HDIM * WDIM);          // 4096
  const int total_threads = planes * NQUAD * NCHUNK;        // 524288
  const int block = 256;
  const int grid = (total_threads + block - 1) / block;     // 2048

  dilated_avg_kernel<<<grid, block, 0, stream>>>(x, out, total_threads);
}

// Round 3
// 88.713 us; speedup vs baseline: 1.5160x; 1.5160x over previous
//
#include <hip/hip_runtime.h>

// DilatedAvgPooling: 3x3, dilation=2, padding=2, stride=1, mean over 9 taps
// (zero-padded taps included). Input (16,256,128,128) fp32 -> same-shape out.
//
// Separable rolling-window with EXPLICIT 4-deep row prefetch pipeline:
//   hs[h][w] = x[h][w-2] + x[h][w] + x[h][w+2]   (zero outside)
//   out[h][w] = (hs[h-2][w] + hs[h][w] + hs[h+2][w]) / 9
// Each thread: 4-wide (float4) strip over a 32-row chunk. Row loads are
// issued PF=4 iterations ahead into statically-indexed register slots
// (full unroll -> no scratch), so ~12 loads stay in flight per wave.
// R1 showed VGPR=20 / VALUBusy 10% / 2.7 TB/s: latency-bound from zero MLP.
// R2: __builtin_nontemporal_store needs native clang vectors, not
// HIP_vector_type -> use ext_vector_type.

typedef float f32x4 __attribute__((ext_vector_type(4)));
typedef float f32x2 __attribute__((ext_vector_type(2)));

#define HDIM 128
#define WDIM 128
#define CHUNK 32          // rows per thread
#define NCHUNK (HDIM / CHUNK)
#define NQUAD (WDIM / 4)  // float4 quads per row
#define PF 4              // prefetch depth in rows (power of 2)

__global__ __launch_bounds__(256) void dilated_avg_kernel(
    const float* __restrict__ x, float* __restrict__ out, int total_threads) {
  int g = blockIdx.x * blockDim.x + threadIdx.x;
  if (g >= total_threads) return;

  const int wq    = g & (NQUAD - 1);          // w-quad index (fastest -> coalesced)
  const int chunk = (g >> 5) & (NCHUNK - 1);  // row chunk
  const int plane = g >> 7;                   // b*C + c

  const float* __restrict__ xp = x + (size_t)plane * (HDIM * WDIM);
  float* __restrict__ op       = out + (size_t)plane * (HDIM * WDIM);

  const int w0 = wq * 4;
  const int h0 = chunk * CHUNK;
  const bool has_l = (w0 >= 2);           // false only for w0 == 0
  const bool has_r = (w0 + 5 < WDIM);     // false only for w0 == 124
  const float ninth = 1.0f / 9.0f;

  // Prefetch ring: slot s = t & 3 holds raw data of input row (h0 - 2 + t).
  f32x4 cbuf[PF];
  f32x2 lbuf[PF];
  f32x2 rbuf[PF];

  auto load_row = [&](int t) {
    const int s  = t & (PF - 1);
    const int rr = h0 - 2 + t;
    f32x4 c4 = {0, 0, 0, 0};
    f32x2 l2 = {0, 0};
    f32x2 r2 = {0, 0};
    if (rr >= 0 && rr < HDIM) {
      const float* row = xp + rr * WDIM + w0;
      c4 = *reinterpret_cast<const f32x4*>(row);
      if (has_l) l2 = *reinterpret_cast<const f32x2*>(row - 2);
      if (has_r) r2 = *reinterpret_cast<const f32x2*>(row + 4);
    }
    cbuf[s] = c4;
    lbuf[s] = l2;
    rbuf[s] = r2;
  };

  #pragma unroll
  for (int t = 0; t < PF; ++t) load_row(t);

  f32x4 p1 = {0,0,0,0}, p2 = {0,0,0,0}, p3 = {0,0,0,0}, p4 = {0,0,0,0};

  // Iteration t consumes row r = h0-2+t (slot t&3), then immediately reissues
  // the slot for row r+PF. Output row (r-2) written when t >= 4.
  #pragma unroll
  for (int t = 0; t < CHUNK + 4; ++t) {
    const int s = t & (PF - 1);
    const f32x4 c4 = cbuf[s];
    const f32x2 l2 = lbuf[s];
    const f32x2 r2 = rbuf[s];

    if (t + PF < CHUNK + 4) load_row(t + PF);  // refill slot 4 rows ahead

    f32x4 cur;
    cur.x = l2.x + c4.x + c4.z;
    cur.y = l2.y + c4.y + c4.w;
    cur.z = c4.x + c4.z + r2.x;
    cur.w = c4.y + c4.w + r2.y;

    if (t >= 4) {
      f32x4 o;
      o.x = (p4.x + p2.x + cur.x) * ninth;
      o.y = (p4.y + p2.y + cur.y) * ninth;
      o.z = (p4.z + p2.z + cur.z) * ninth;
      o.w = (p4.w + p2.w + cur.w) * ninth;
      const int rr = h0 - 2 + t;
      // Output is never re-read: nontemporal store keeps input resident in L3.
      __builtin_nontemporal_store(o, reinterpret_cast<f32x4*>(op + (rr - 2) * WDIM + w0));
    }
    p4 = p3; p3 = p2; p2 = p1; p1 = cur;
  }
}

extern "C" void kernel_launch(void* const* d_in, const int* in_sizes, int n_in,
                              void* d_out, int out_size, void* d_ws, size_t ws_size,
                              hipStream_t stream) {
  const float* x = (const float*)d_in[0];
  float* out = (float*)d_out;

  const int planes = in_sizes[0] / (HDIM * WDIM);          // 4096
  const int total_threads = planes * NQUAD * NCHUNK;        // 524288
  const int block = 256;
  const int grid = (total_threads + block - 1) / block;     // 2048

  dilated_avg_kernel<<<grid, block, 0, stream>>>(x, out, total_threads);
}

// Round 4
// 84.524 us; speedup vs baseline: 1.5912x; 1.0496x over previous
//
#include <hip/hip_runtime.h>

// DilatedAvgPooling: 3x3, dilation=2, padding=2, stride=1, mean over 9 taps
// (zero-padded taps included). Input (16,256,128,128) fp32 -> same-shape out.
//
// Separable rolling-window, 4-deep register prefetch ring (R3: 155->88.7us).
// R4 changes:
//  - halo float2 loads replaced with intra-wave shuffles: lanes 0..31 of a
//    wave are the 32 float4-quads of one row, so x[w0-2],x[w0-1] live in
//    lane-1's c4.zw and x[w0+4],x[w0+5] in lane+1's c4.xy. 1 load instr /
//    16B per output quad instead of 3 / 32B.
//  - CHUNK 32 -> 64: vertical halo re-reads 12.5% -> 6%; 16 waves/CU with
//    4 x 1KB wave-loads in flight each (64KB/CU >> BW*latency ~5KB).

typedef float f32x4 __attribute__((ext_vector_type(4)));

#define HDIM 128
#define WDIM 128
#define CHUNK 64          // rows per thread
#define NCHUNK (HDIM / CHUNK)
#define NQUAD (WDIM / 4)  // float4 quads per row (= 32 = half-wave)
#define PF 4              // prefetch depth in rows (power of 2)

__global__ __launch_bounds__(256) void dilated_avg_kernel(
    const float* __restrict__ x, float* __restrict__ out, int total_threads) {
  int g = blockIdx.x * blockDim.x + threadIdx.x;
  if (g >= total_threads) return;

  const int wq    = g & (NQUAD - 1);          // w-quad index (fastest -> coalesced)
  const int chunk = (g >> 5) & (NCHUNK - 1);  // row chunk
  const int plane = g >> 6;                   // b*C + c   (5 + log2(NCHUNK) bits)

  const float* __restrict__ xp = x + (size_t)plane * (HDIM * WDIM);
  float* __restrict__ op       = out + (size_t)plane * (HDIM * WDIM);

  const int w0 = wq * 4;
  const int h0 = chunk * CHUNK;
  const bool has_l = (wq != 0);            // w0 == 0   -> left taps are pad
  const bool has_r = (wq != NQUAD - 1);    // w0 == 124 -> right taps are pad
  const float ninth = 1.0f / 9.0f;

  // Prefetch ring: slot s = t & 3 holds the center float4 of row (h0 - 2 + t).
  f32x4 cbuf[PF];

  auto load_row = [&](int t) {
    const int s  = t & (PF - 1);
    const int rr = h0 - 2 + t;
    f32x4 c4 = {0, 0, 0, 0};
    if (rr >= 0 && rr < HDIM) {
      c4 = *reinterpret_cast<const f32x4*>(xp + rr * WDIM + w0);
    }
    cbuf[s] = c4;
  };

  #pragma unroll
  for (int t = 0; t < PF; ++t) load_row(t);

  f32x4 p1 = {0,0,0,0}, p2 = {0,0,0,0}, p3 = {0,0,0,0}, p4 = {0,0,0,0};

  // Iteration t consumes row r = h0-2+t (slot t&3), reissues slot for r+PF.
  // Output row (r-2) written when t >= 4.
  #pragma unroll
  for (int t = 0; t < CHUNK + 4; ++t) {
    const int s = t & (PF - 1);
    const f32x4 c4 = cbuf[s];

    if (t + PF < CHUNK + 4) load_row(t + PF);  // refill slot PF rows ahead

    // Halo via shuffle (width 32: lanes 0..31 / 32..63 are separate rows).
    const float lx = __shfl_up(c4.z, 1, 32);   // lane-1's x[w0-2]
    const float ly = __shfl_up(c4.w, 1, 32);   // lane-1's x[w0-1]
    const float rx = __shfl_down(c4.x, 1, 32); // lane+1's x[w0+4]
    const float ry = __shfl_down(c4.y, 1, 32); // lane+1's x[w0+5]
    const float l2x = has_l ? lx : 0.0f;
    const float l2y = has_l ? ly : 0.0f;
    const float r2x = has_r ? rx : 0.0f;
    const float r2y = has_r ? ry : 0.0f;

    f32x4 cur;
    cur.x = l2x + c4.x + c4.z;
    cur.y = l2y + c4.y + c4.w;
    cur.z = c4.x + c4.z + r2x;
    cur.w = c4.y + c4.w + r2y;

    if (t >= 4) {
      f32x4 o;
      o.x = (p4.x + p2.x + cur.x) * ninth;
      o.y = (p4.y + p2.y + cur.y) * ninth;
      o.z = (p4.z + p2.z + cur.z) * ninth;
      o.w = (p4.w + p2.w + cur.w) * ninth;
      const int rr = h0 - 2 + t;
      // Output is never re-read: nontemporal store keeps input resident in L3.
      __builtin_nontemporal_store(o, reinterpret_cast<f32x4*>(op + (rr - 2) * WDIM + w0));
    }
    p4 = p3; p3 = p2; p2 = p1; p1 = cur;
  }
}

extern "C" void kernel_launch(void* const* d_in, const int* in_sizes, int n_in,
                              void* d_out, int out_size, void* d_ws, size_t ws_size,
                              hipStream_t stream) {
  const float* x = (const float*)d_in[0];
  float* out = (float*)d_out;

  const int planes = in_sizes[0] / (HDIM * WDIM);           // 4096
  const int total_threads = planes * NQUAD * NCHUNK;         // 262144
  const int block = 256;
  const int grid = (total_threads + block - 1) / block;      // 1024

  dilated_avg_kernel<<<grid, block, 0, stream>>>(x, out, total_threads);
}